// Round 1
// 1216.025 us; speedup vs baseline: 1.2038x; 1.2038x over previous
//
#include <hip/hip_runtime.h>

// Problem constants (B, D, H, O, T, NOPS from reference)
static constexpr int Bn = 8192;
static constexpr int Dd = 1024;
static constexpr int Hh = 2048;
static constexpr int Oo = 1024;
static constexpr int Tt = 4;
static constexpr int NO = 3;
#define TB 256

typedef __attribute__((ext_vector_type(8))) short bf16x8;
typedef __attribute__((ext_vector_type(4))) float f32x4;

__device__ __forceinline__ ushort f2bf(float f) {
  union { float f; unsigned u; } v; v.f = f;
  return (ushort)((v.u + 0x7FFFu + ((v.u >> 16) & 1u)) >> 16);  // RNE
}

// Top-2 of logits per temper (softmax is monotonic; jax top_k ties -> lower idx).
__global__ void top2_kernel(const float* __restrict__ logits, int* __restrict__ idx) {
  if (threadIdx.x == 0 && blockIdx.x == 0) {
    for (int t = 0; t < Tt; ++t) {
      const float* lg = logits + t * NO;
      int i0 = 0;
      for (int k = 1; k < NO; ++k) if (lg[k] > lg[i0]) i0 = k;
      int i1 = -1;
      for (int k = 0; k < NO; ++k) {
        if (k == i0) continue;
        if (i1 < 0 || lg[k] > lg[i1]) i1 = k;
      }
      idx[2 * t] = i0;
      idx[2 * t + 1] = i1;
    }
  }
}

__global__ void cvt_bf16(const float* __restrict__ src, ushort* __restrict__ dst, int n4) {
  int i = blockIdx.x * blockDim.x + threadIdx.x;
  if (i >= n4) return;
  float4 v = ((const float4*)src)[i];
  ((ushort4*)dst)[i] = make_ushort4(f2bf(v.x), f2bf(v.y), f2bf(v.z), f2bf(v.w));
}

// Convert the two routed operator weight matrices (indices live on device).
__global__ void cvt_sel(const float* __restrict__ WopT, const int* __restrict__ idx2,
                        ushort* __restrict__ Wa, ushort* __restrict__ Wb, int n4) {
  int i = blockIdx.x * blockDim.x + threadIdx.x;
  if (i >= n4) return;
  size_t n = (size_t)n4 * 4;
  float4 va = ((const float4*)(WopT + (size_t)idx2[0] * n))[i];
  float4 vb = ((const float4*)(WopT + (size_t)idx2[1] * n))[i];
  ((ushort4*)Wa)[i] = make_ushort4(f2bf(va.x), f2bf(va.y), f2bf(va.z), f2bf(va.w));
  ((ushort4*)Wb)[i] = make_ushort4(f2bf(vb.x), f2bf(vb.y), f2bf(vb.z), f2bf(vb.w));
}

#define ISSUE_TILE(kk, p)                                                                   \
  do {                                                                                      \
    __builtin_amdgcn_global_load_lds(                                                       \
        (const __attribute__((address_space(1))) void*)(a0 + (kk)),                         \
        (__attribute__((address_space(3))) void*)(&As[p][w * 512]), 16, 0, 0);              \
    __builtin_amdgcn_global_load_lds(                                                       \
        (const __attribute__((address_space(1))) void*)(a1 + (kk)),                         \
        (__attribute__((address_space(3))) void*)(&As[p][2048 + w * 512]), 16, 0, 0);       \
    __builtin_amdgcn_global_load_lds(                                                       \
        (const __attribute__((address_space(1))) void*)(b0 + (kk)),                         \
        (__attribute__((address_space(3))) void*)(&Bs[p][w * 512]), 16, 0, 0);              \
    __builtin_amdgcn_global_load_lds(                                                       \
        (const __attribute__((address_space(1))) void*)(b1 + (kk)),                         \
        (__attribute__((address_space(3))) void*)(&Bs[p][2048 + w * 512]), 16, 0, 0);       \
  } while (0)

// C[M,N] = A[M,K] @ B[N,K]^T, bf16 in, fp32 accumulate.  (kept for readout N=1024)
// EP 0: C(bf16) = relu(acc + bias[col]); EP 1: C(f32) = acc + bias; EP 2: C(f32) += acc
// 128x128 tile, BK=32, 4 waves x (4x4 of 16x16x32 MFMA). m97-class structure.
template <int EP>
__global__ __launch_bounds__(TB) void gemm_bt(
    const ushort* __restrict__ A, int lda,
    const ushort* __restrict__ B, int ldb,
    const float* __restrict__ bias, const int* __restrict__ idxp, int sel, int bstride,
    void* __restrict__ Cv, int ldc, int K) {
  __shared__ __align__(16) ushort As[2][128 * 32];
  __shared__ __align__(16) ushort Bs[2][128 * 32];
  const int tid = threadIdx.x;
  const int w = tid >> 6;
  const int lane = tid & 63;
  const int quad = lane >> 4;
  const int l16 = lane & 15;

  const int GX = gridDim.x, GY = gridDim.y;
  const int f = blockIdx.y * GX + blockIdx.x;
  const int xcd = f & 7;
  const int s = f >> 3;
  const int pxc = (GX >= 16) ? 2 : 1;
  const int pw = GX / pxc;
  const int ph = (GY * pxc) >> 3;
  const int bx = (xcd % pxc) * pw + (s % pw);
  const int by = (xcd / pxc) * ph + (s / pw);
  const int m0 = by * 128;
  const int n0 = bx * 128;
  const int wm = (w >> 1) * 64;
  const int wn = (w & 1) * 64;

  f32x4 acc[4][4];
#pragma unroll
  for (int i = 0; i < 4; ++i)
#pragma unroll
    for (int j = 0; j < 4; ++j)
#pragma unroll
      for (int r = 0; r < 4; ++r) acc[i][j][r] = 0.f;

  const int srow = tid >> 2;
  const int skc = ((tid & 3) ^ ((tid >> 3) & 3)) * 8;
  const ushort* a0 = A + (size_t)(m0 + srow) * lda + skc;
  const ushort* a1 = A + (size_t)(m0 + 64 + srow) * lda + skc;
  const ushort* b0 = B + (size_t)(n0 + srow) * ldb + skc;
  const ushort* b1 = B + (size_t)(n0 + 64 + srow) * ldb + skc;

  const int fq = (quad ^ ((l16 >> 1) & 3)) * 8;

  const int niter = K >> 5;
  ISSUE_TILE(0, 0);
  for (int it = 0; it < niter; ++it) {
    const int p = it & 1;
    __syncthreads();
    if (it + 1 < niter) ISSUE_TILE((it + 1) << 5, p ^ 1);

    bf16x8 af[4], bfr[4];
#pragma unroll
    for (int i = 0; i < 4; ++i)
      af[i] = *(const bf16x8*)&As[p][((wm >> 4) + i) * 512 + l16 * 32 + fq];
#pragma unroll
    for (int j = 0; j < 4; ++j)
      bfr[j] = *(const bf16x8*)&Bs[p][((wn >> 4) + j) * 512 + l16 * 32 + fq];
#pragma unroll
    for (int i = 0; i < 4; ++i)
#pragma unroll
      for (int j = 0; j < 4; ++j)
        acc[i][j] = __builtin_amdgcn_mfma_f32_16x16x32_bf16(af[i], bfr[j], acc[i][j], 0, 0, 0);
  }

  const float* bb = bias;
  if (EP == 0 && idxp) bb += (size_t)idxp[sel] * bstride;

#pragma unroll
  for (int i = 0; i < 4; ++i) {
#pragma unroll
    for (int j = 0; j < 4; ++j) {
      const int col = n0 + wn + j * 16 + l16;
      const float bv = (EP == 2) ? 0.f : bb[col];
#pragma unroll
      for (int r = 0; r < 4; ++r) {
        const int row = m0 + wm + i * 16 + quad * 4 + r;
        float v = acc[i][j][r] + bv;
        if (EP == 0) {
          v = v > 0.f ? v : 0.f;
          ((ushort*)Cv)[(size_t)row * ldc + col] = f2bf(v);
        } else if (EP == 1) {
          ((float*)Cv)[(size_t)row * ldc + col] = v;
        } else {
          ((float*)Cv)[(size_t)row * ldc + col] += v;
        }
      }
    }
  }
}

// ---------------------------------------------------------------------------
// 256x256 8-phase GEMM (T2+T3+T4+T5 template, plain HIP).
// 512 thr = 8 waves (2M x 4N), per-wave 128x64 C. BK=64, 2 K-tiles/iter.
// LDS 128 KiB: 2 buf x (A 256x64 + B 256x64) bf16, each as 2 half-tiles of
// 128 rows x 8 chunks(16B); chunk XOR-swizzled by (row&7) -> conflict-free
// ds_read_b128 at 128B row stride (G4 fix) AND linear global_load_lds dest
// (inverse swizzle applied on the per-lane GLOBAL address, m173 pattern).
// Per phase: {ds_read subtile || stage 1 half-tile (2 x gload_lds w16)
//             -> s_barrier -> lgkmcnt(0) -> setprio(1) 16xMFMA setprio(0)
//             -> s_barrier}.  vmcnt(4) ONLY at phases 4 and 8 (2 half-tiles
// = 4 loads stay in flight across barriers).  Region-liveness schedule:
//  ph1:stage t+1.A0(buf1)  ph2:t+1.A1  ph3:t+2.B0(buf0, dead after ph2)
//  ph4:t+2.B1  ph5:t+2.A0(dead after ph3)  ph6:t+2.A1  ph7:t+3.B0(buf1)
//  ph8:t+3.B1.  K-tail prefetches clamp the tile index (harmless re-reads,
// keeps vmcnt counts uniform).  sched_barrier(0) after the vmcnt-phase
// barriers pins the only unsafe compiler hoist (next RD into vmcnt->bar gap).
// ---------------------------------------------------------------------------
#define BAR() __builtin_amdgcn_s_barrier()
#define SCHEDB() __builtin_amdgcn_sched_barrier(0)
#define WAITLGKM() asm volatile("s_waitcnt lgkmcnt(0)" ::: "memory")
#define WAITVM(N) asm volatile("s_waitcnt vmcnt(" #N ")" ::: "memory")

#define STG(BASE, LD, ARR, P, H, KT)                                                        \
  do {                                                                                      \
    const int kt_ = ((KT) < ntile) ? (KT) : (ntile - 1);                                    \
    const ushort* g_ = (BASE) + (size_t)(H) * 128 * (LD) + (size_t)kt_ * 64;                \
    __builtin_amdgcn_global_load_lds(                                                       \
        (const __attribute__((address_space(1))) void*)g_,                                  \
        (__attribute__((address_space(3))) void*)&ARR[(P) * 16384 + (H) * 8192 + w * 512],  \
        16, 0, 0);                                                                          \
    __builtin_amdgcn_global_load_lds(                                                       \
        (const __attribute__((address_space(1))) void*)(g_ + (size_t)64 * (LD)),            \
        (__attribute__((address_space(3))) void*)&ARR[(P) * 16384 + (H) * 8192 + 4096 +     \
                                                      w * 512],                             \
        16, 0, 0);                                                                          \
  } while (0)

#define RD_A(P, MH)                                                                         \
  do {                                                                                      \
    _Pragma("unroll") for (int mf = 0; mf < 4; ++mf)                                        \
    _Pragma("unroll") for (int kk = 0; kk < 2; ++kk)                                        \
        af[mf][kk] = *(const bf16x8*)&As[(P) * 16384 + ak[kk] + ((MH) * 4 + mf) * 1024];    \
  } while (0)

#define RD_B(P, NH)                                                                         \
  do {                                                                                      \
    _Pragma("unroll") for (int nf = 0; nf < 2; ++nf)                                        \
    _Pragma("unroll") for (int kk = 0; kk < 2; ++kk)                                        \
        bfr[(NH) * 2 + nf][kk] =                                                            \
            *(const bf16x8*)&Bs[(P) * 16384 + bk[kk] + ((NH) * 2 + nf) * 1024];             \
  } while (0)

#define MFMA_Q(MH, NH)                                                                      \
  do {                                                                                      \
    __builtin_amdgcn_s_setprio(1);                                                          \
    _Pragma("unroll") for (int mf = 0; mf < 4; ++mf)                                        \
    _Pragma("unroll") for (int nf = 0; nf < 2; ++nf)                                        \
    _Pragma("unroll") for (int kk = 0; kk < 2; ++kk)                                        \
        acc[(MH) * 4 + mf][(NH) * 2 + nf] = __builtin_amdgcn_mfma_f32_16x16x32_bf16(        \
            af[mf][kk], bfr[(NH) * 2 + nf][kk], acc[(MH) * 4 + mf][(NH) * 2 + nf], 0, 0, 0);\
    __builtin_amdgcn_s_setprio(0);                                                          \
  } while (0)

template <int EP>
__global__ __launch_bounds__(512, 2) void gemm256(
    const ushort* __restrict__ A, int lda,
    const ushort* __restrict__ B, int ldb,
    const float* __restrict__ bias, const int* __restrict__ idxp, int sel, int bstride,
    void* __restrict__ Cv, int ldc, int K) {
  __shared__ __align__(16) ushort As[32768];  // 2 buf x 2 half x 128row x 8chunk x 8 bf16
  __shared__ __align__(16) ushort Bs[32768];
  const int tid = threadIdx.x;
  const int w = tid >> 6;
  const int lane = tid & 63;
  const int quad = lane >> 4;
  const int l16 = lane & 15;
  const int wr = w >> 2;   // 0..1 : wave row (128 rows)
  const int wc = w & 3;    // 0..3 : wave col (64 cols)

  // Bijective XCD swizzle (m204): each XCD owns a contiguous wg chunk.
  const int GX = gridDim.x;
  const int nwg = GX * gridDim.y;
  const int fid = blockIdx.y * GX + blockIdx.x;
  const int q8 = nwg >> 3, r8 = nwg & 7, xcd = fid & 7, ser = fid >> 3;
  const int wg = (xcd < r8 ? xcd * (q8 + 1) : r8 * (q8 + 1) + (xcd - r8) * q8) + ser;
  const int m0 = (wg / GX) * 256;
  const int n0 = (wg % GX) * 256;

  f32x4 acc[8][4];
#pragma unroll
  for (int i = 0; i < 8; ++i)
#pragma unroll
    for (int j = 0; j < 4; ++j)
#pragma unroll
      for (int r = 0; r < 4; ++r) acc[i][j][r] = 0.f;

  // Staging: thread -> (row = tid>>3 [+64 for 2nd load], chunk = tid&7),
  // global k-chunk = chunk ^ (row&7); LDS dest stays linear (wave base + lane*16).
  const int srow = tid >> 3;
  const int scol = (tid & 7) ^ (srow & 7);
  const ushort* Abase = A + (size_t)(m0 + srow) * lda + scol * 8;
  const ushort* Bbase = B + (size_t)(n0 + srow) * ldb + scol * 8;
  const int ntile = K >> 6;   // 64-wide K tiles (K = 1024 or 2048 -> even count)
  const int ni = ntile >> 1;  // 2 tiles per iteration

  // ds_read offsets (ushort units): row*64 + (chunk ^ (row&7))*8, row = frag*16+l16.
  int ak[2], bk[2];
#pragma unroll
  for (int kk = 0; kk < 2; ++kk) {
    const int ch = ((kk * 4 + quad) ^ (l16 & 7)) * 8;
    ak[kk] = wr * 8192 + l16 * 64 + ch;
    bk[kk] = (wc >> 1) * 8192 + ((wc & 1) * 64 + l16) * 64 + ch;
  }

  // Prologue: tile0 (A0,A1,B0,B1) + tile1 (B0,B1); wait for tile0 only.
  STG(Abase, lda, As, 0, 0, 0);
  STG(Abase, lda, As, 0, 1, 0);
  STG(Bbase, ldb, Bs, 0, 0, 0);
  STG(Bbase, ldb, Bs, 0, 1, 0);
  STG(Bbase, ldb, Bs, 1, 0, 1);
  STG(Bbase, ldb, Bs, 1, 1, 1);
  WAITVM(4);
  BAR();
  SCHEDB();

  bf16x8 af[4][2], bfr[4][2];
  for (int i = 0; i < ni; ++i) {
    const int t = 2 * i;
    // ---- tile t (buf0) ----
    // ph1: quadrant (mh0,nh0)
    RD_A(0, 0); RD_B(0, 0);
    STG(Abase, lda, As, 1, 0, t + 1);
    BAR(); WAITLGKM();
    MFMA_Q(0, 0);
    BAR();
    // ph2: (mh0,nh1)
    RD_B(0, 1);
    STG(Abase, lda, As, 1, 1, t + 1);
    BAR(); WAITLGKM();
    MFMA_Q(0, 1);
    BAR();
    // ph3: (mh1,nh0)
    RD_A(0, 1);
    STG(Bbase, ldb, Bs, 0, 0, t + 2);
    BAR(); WAITLGKM();
    MFMA_Q(1, 0);
    BAR();
    // ph4: (mh1,nh1) — counted vmcnt: leave t+2.B0/B1 (4 loads) in flight
    STG(Bbase, ldb, Bs, 0, 1, t + 2);
    WAITVM(4);
    BAR();
    SCHEDB();
    MFMA_Q(1, 1);
    BAR();
    // ---- tile t+1 (buf1) ----
    // ph5
    RD_A(1, 0); RD_B(1, 0);
    STG(Abase, lda, As, 0, 0, t + 2);
    BAR(); WAITLGKM();
    MFMA_Q(0, 0);
    BAR();
    // ph6
    RD_B(1, 1);
    STG(Abase, lda, As, 0, 1, t + 2);
    BAR(); WAITLGKM();
    MFMA_Q(0, 1);
    BAR();
    // ph7
    RD_A(1, 1);
    STG(Bbase, ldb, Bs, 1, 0, t + 3);
    BAR(); WAITLGKM();
    MFMA_Q(1, 0);
    BAR();
    // ph8 — counted vmcnt: leave t+3.B0/B1 in flight
    STG(Bbase, ldb, Bs, 1, 1, t + 3);
    WAITVM(4);
    BAR();
    SCHEDB();
    MFMA_Q(1, 1);
    BAR();
  }
  WAITVM(0);  // drain clamped tail prefetches before LDS teardown
  BAR();

  const float* bb = bias;
  if (EP == 0 && idxp) bb += (size_t)idxp[sel] * bstride;

  // C/D layout: col = lane&15, row = quad*4 + r (verified mapping)
#pragma unroll
  for (int mf = 0; mf < 8; ++mf) {
#pragma unroll
    for (int nf = 0; nf < 4; ++nf) {
      const int col = n0 + wc * 64 + nf * 16 + l16;
      const float bv = (EP == 2) ? 0.f : bb[col];
#pragma unroll
      for (int r = 0; r < 4; ++r) {
        const int row = m0 + wr * 128 + mf * 16 + quad * 4 + r;
        float v = acc[mf][nf][r] + bv;
        if (EP == 0) {
          v = v > 0.f ? v : 0.f;
          ((ushort*)Cv)[(size_t)row * ldc + col] = f2bf(v);
        } else if (EP == 1) {
          ((float*)Cv)[(size_t)row * ldc + col] = v;
        } else {
          ((float*)Cv)[(size_t)row * ldc + col] += v;
        }
      }
    }
  }
}

extern "C" void kernel_launch(void* const* d_in, const int* in_sizes, int n_in,
                              void* d_out, int out_size, void* d_ws, size_t ws_size,
                              hipStream_t stream) {
  const float* x      = (const float*)d_in[0];
  const float* Wp     = (const float*)d_in[1];
  const float* bp     = (const float*)d_in[2];
  const float* Wop    = (const float*)d_in[3];
  const float* bop    = (const float*)d_in[4];
  const float* logits = (const float*)d_in[5];
  const float* Wr     = (const float*)d_in[6];
  const float* br     = (const float*)d_in[7];
  float* out = (float*)d_out;

  // Workspace layout (~128.25 MB total)
  char* ws = (char*)d_ws;
  size_t off = 0;
  int* idx = (int*)ws;                          off += 256;
  ushort* xb   = (ushort*)(ws + off);           off += (size_t)Bn * Dd * 2;        // 16 MB
  ushort* WpB  = (ushort*)(ws + off);           off += (size_t)Tt * Hh * Dd * 2;   // 16 MB
  ushort* WrB  = (ushort*)(ws + off);           off += (size_t)Oo * Tt * Hh * 2;   // 16 MB
  ushort* WaB  = (ushort*)(ws + off);           off += (size_t)Hh * Hh * 2;        // 8 MB
  ushort* WbB  = (ushort*)(ws + off);           off += (size_t)Hh * Hh * 2;        // 8 MB
  ushort* bufA = (ushort*)(ws + off);           off += (size_t)Bn * Hh * 2;        // 32 MB
  ushort* bufB = (ushort*)(ws + off);           off += (size_t)Bn * Hh * 2;        // 32 MB

  top2_kernel<<<1, 64, 0, stream>>>(logits, idx);
  {
    int n4 = Bn * Dd / 4;
    cvt_bf16<<<(n4 + TB - 1) / TB, TB, 0, stream>>>(x, xb, n4);
  }
  {
    int n4 = Tt * Hh * Dd / 4;
    cvt_bf16<<<(n4 + TB - 1) / TB, TB, 0, stream>>>(Wp, WpB, n4);
  }
  {
    int n4 = Oo * Tt * Hh / 4;
    cvt_bf16<<<(n4 + TB - 1) / TB, TB, 0, stream>>>(Wr, WrB, n4);
  }

  dim3 g256(Hh / 256, Bn / 256);  // 8 x 32 = 256 wgs for N=2048 GEMMs
  dim3 gOB(Oo / 128, Bn / 128);   // readout N=1024 on 128^2 kernel (512 wgs)

  for (int t = 0; t < Tt; ++t) {
    int n4 = Hh * Hh / 4;
    cvt_sel<<<(n4 + TB - 1) / TB, TB, 0, stream>>>(Wop + (size_t)t * NO * Hh * Hh, idx + 2 * t,
                                                   WaB, WbB, n4);
    // a1 = relu(x @ Wp_t^T + bp_t)               [B,H] bf16
    gemm256<0><<<g256, 512, 0, stream>>>(xb, Dd, WpB + (size_t)t * Hh * Dd, Dd,
                                         bp + (size_t)t * Hh, nullptr, 0, 0, bufA, Hh, Dd);
    // h  = relu(a1 @ Wa^T + ba)                  [B,H] bf16
    gemm256<0><<<g256, 512, 0, stream>>>(bufA, Hh, WaB, Hh,
                                         bop + (size_t)t * NO * Hh, idx + 2 * t, 0, Hh,
                                         bufB, Hh, Hh);
    // o  = relu(h @ Wb^T + bb)                   [B,H] bf16 (double relu collapses)
    gemm256<0><<<g256, 512, 0, stream>>>(bufB, Hh, WbB, Hh,
                                         bop + (size_t)t * NO * Hh, idx + 2 * t, 1, Hh,
                                         bufA, Hh, Hh);
    // out (+)= o @ Wr[:, t*H:(t+1)*H]^T  (+ br at t=0)
    if (t == 0)
      gemm_bt<1><<<gOB, TB, 0, stream>>>(bufA, Hh, WrB + (size_t)t * Hh, Tt * Hh,
                                         br, nullptr, 0, 0, out, Oo, Hh);
    else
      gemm_bt<2><<<gOB, TB, 0, stream>>>(bufA, Hh, WrB + (size_t)t * Hh, Tt * Hh,
                                         nullptr, nullptr, 0, 0, out, Oo, Hh);
  }
}

// Round 2
// 1196.850 us; speedup vs baseline: 1.2231x; 1.0160x over previous
//
#include <hip/hip_runtime.h>

// Problem constants (B, D, H, O, T, NOPS from reference)
static constexpr int Bn = 8192;
static constexpr int Dd = 1024;
static constexpr int Hh = 2048;
static constexpr int Oo = 1024;
static constexpr int Tt = 4;
static constexpr int NO = 3;
static constexpr int TH = Tt * Hh;  // 8192
#define TB 256

typedef __attribute__((ext_vector_type(8))) short bf16x8;
typedef __attribute__((ext_vector_type(4))) float f32x4;

__device__ __forceinline__ ushort f2bf(float f) {
  union { float f; unsigned u; } v; v.f = f;
  return (ushort)((v.u + 0x7FFFu + ((v.u >> 16) & 1u)) >> 16);  // RNE
}

// Top-2 of logits per temper (softmax is monotonic; jax top_k ties -> lower idx).
__global__ void top2_kernel(const float* __restrict__ logits, int* __restrict__ idx) {
  if (threadIdx.x == 0 && blockIdx.x == 0) {
    for (int t = 0; t < Tt; ++t) {
      const float* lg = logits + t * NO;
      int i0 = 0;
      for (int k = 1; k < NO; ++k) if (lg[k] > lg[i0]) i0 = k;
      int i1 = -1;
      for (int k = 0; k < NO; ++k) {
        if (k == i0) continue;
        if (i1 < 0 || lg[k] > lg[i1]) i1 = k;
      }
      idx[2 * t] = i0;
      idx[2 * t + 1] = i1;
    }
  }
}

__global__ void cvt_bf16(const float* __restrict__ src, ushort* __restrict__ dst, int n4) {
  int i = blockIdx.x * blockDim.x + threadIdx.x;
  if (i >= n4) return;
  float4 v = ((const float4*)src)[i];
  ((ushort4*)dst)[i] = make_ushort4(f2bf(v.x), f2bf(v.y), f2bf(v.z), f2bf(v.w));
}

// Convert the two routed operator matrices for ONE temper (fallback path).
__global__ void cvt_sel(const float* __restrict__ WopT, const int* __restrict__ idx2,
                        ushort* __restrict__ Wa, ushort* __restrict__ Wb, int n4) {
  int i = blockIdx.x * blockDim.x + threadIdx.x;
  if (i >= n4) return;
  size_t n = (size_t)n4 * 4;
  float4 va = ((const float4*)(WopT + (size_t)idx2[0] * n))[i];
  float4 vb = ((const float4*)(WopT + (size_t)idx2[1] * n))[i];
  ((ushort4*)Wa)[i] = make_ushort4(f2bf(va.x), f2bf(va.y), f2bf(va.z), f2bf(va.w));
  ((ushort4*)Wb)[i] = make_ushort4(f2bf(vb.x), f2bf(vb.y), f2bf(vb.z), f2bf(vb.w));
}

// Convert ALL 8 routed matrices (fused path). z = t*2 + slot -> W8[z] layout,
// so Wa_t lives at W8 + (2t)*H*H and Wb_t at W8 + (2t+1)*H*H.
__global__ void cvt_sel8(const float* __restrict__ Wop, const int* __restrict__ idx,
                         ushort* __restrict__ W8, int n4) {
  int i = blockIdx.x * blockDim.x + threadIdx.x;
  if (i >= n4) return;
  int z = blockIdx.z;
  int t = z >> 1, slot = z & 1;
  int op = idx[2 * t + slot];
  const float4* src = (const float4*)(Wop + ((size_t)t * NO + op) * Hh * Hh);
  float4 v = src[i];
  ((ushort4*)(W8 + (size_t)z * Hh * Hh))[i] =
      make_ushort4(f2bf(v.x), f2bf(v.y), f2bf(v.z), f2bf(v.w));
}

// out += p1 (split-K reduction for the fused readout)
__global__ void add_f32(float* __restrict__ out, const float* __restrict__ p1, int n4) {
  int i = blockIdx.x * blockDim.x + threadIdx.x;
  if (i >= n4) return;
  float4 a = ((const float4*)out)[i];
  float4 b = ((const float4*)p1)[i];
  a.x += b.x; a.y += b.y; a.z += b.z; a.w += b.w;
  ((float4*)out)[i] = a;
}

#define ISSUE_TILE(kk, p)                                                                   \
  do {                                                                                      \
    __builtin_amdgcn_global_load_lds(                                                       \
        (const __attribute__((address_space(1))) void*)(a0 + (kk)),                         \
        (__attribute__((address_space(3))) void*)(&As[p][w * 512]), 16, 0, 0);              \
    __builtin_amdgcn_global_load_lds(                                                       \
        (const __attribute__((address_space(1))) void*)(a1 + (kk)),                         \
        (__attribute__((address_space(3))) void*)(&As[p][2048 + w * 512]), 16, 0, 0);       \
    __builtin_amdgcn_global_load_lds(                                                       \
        (const __attribute__((address_space(1))) void*)(b0 + (kk)),                         \
        (__attribute__((address_space(3))) void*)(&Bs[p][w * 512]), 16, 0, 0);              \
    __builtin_amdgcn_global_load_lds(                                                       \
        (const __attribute__((address_space(1))) void*)(b1 + (kk)),                         \
        (__attribute__((address_space(3))) void*)(&Bs[p][2048 + w * 512]), 16, 0, 0);       \
  } while (0)

// 128x128-tile m97-class GEMM (fallback readout only).
template <int EP>
__global__ __launch_bounds__(TB) void gemm_bt(
    const ushort* __restrict__ A, int lda,
    const ushort* __restrict__ B, int ldb,
    const float* __restrict__ bias, const int* __restrict__ idxp, int sel, int bstride,
    void* __restrict__ Cv, int ldc, int K) {
  __shared__ __align__(16) ushort As[2][128 * 32];
  __shared__ __align__(16) ushort Bs[2][128 * 32];
  const int tid = threadIdx.x;
  const int w = tid >> 6;
  const int lane = tid & 63;
  const int quad = lane >> 4;
  const int l16 = lane & 15;

  const int GX = gridDim.x, GY = gridDim.y;
  const int f = blockIdx.y * GX + blockIdx.x;
  const int xcd = f & 7;
  const int s = f >> 3;
  const int pxc = (GX >= 16) ? 2 : 1;
  const int pw = GX / pxc;
  const int ph = (GY * pxc) >> 3;
  const int bx = (xcd % pxc) * pw + (s % pw);
  const int by = (xcd / pxc) * ph + (s / pw);
  const int m0 = by * 128;
  const int n0 = bx * 128;
  const int wm = (w >> 1) * 64;
  const int wn = (w & 1) * 64;

  f32x4 acc[4][4];
#pragma unroll
  for (int i = 0; i < 4; ++i)
#pragma unroll
    for (int j = 0; j < 4; ++j)
#pragma unroll
      for (int r = 0; r < 4; ++r) acc[i][j][r] = 0.f;

  const int srow = tid >> 2;
  const int skc = ((tid & 3) ^ ((tid >> 3) & 3)) * 8;
  const ushort* a0 = A + (size_t)(m0 + srow) * lda + skc;
  const ushort* a1 = A + (size_t)(m0 + 64 + srow) * lda + skc;
  const ushort* b0 = B + (size_t)(n0 + srow) * ldb + skc;
  const ushort* b1 = B + (size_t)(n0 + 64 + srow) * ldb + skc;

  const int fq = (quad ^ ((l16 >> 1) & 3)) * 8;

  const int niter = K >> 5;
  ISSUE_TILE(0, 0);
  for (int it = 0; it < niter; ++it) {
    const int p = it & 1;
    __syncthreads();
    if (it + 1 < niter) ISSUE_TILE((it + 1) << 5, p ^ 1);

    bf16x8 af[4], bfr[4];
#pragma unroll
    for (int i = 0; i < 4; ++i)
      af[i] = *(const bf16x8*)&As[p][((wm >> 4) + i) * 512 + l16 * 32 + fq];
#pragma unroll
    for (int j = 0; j < 4; ++j)
      bfr[j] = *(const bf16x8*)&Bs[p][((wn >> 4) + j) * 512 + l16 * 32 + fq];
#pragma unroll
    for (int i = 0; i < 4; ++i)
#pragma unroll
      for (int j = 0; j < 4; ++j)
        acc[i][j] = __builtin_amdgcn_mfma_f32_16x16x32_bf16(af[i], bfr[j], acc[i][j], 0, 0, 0);
  }

  const float* bb = bias;
  if (EP == 0 && idxp) bb += (size_t)idxp[sel] * bstride;

#pragma unroll
  for (int i = 0; i < 4; ++i) {
#pragma unroll
    for (int j = 0; j < 4; ++j) {
      const int col = n0 + wn + j * 16 + l16;
      const float bv = (EP == 2 || !bias) ? 0.f : bb[col];
#pragma unroll
      for (int r = 0; r < 4; ++r) {
        const int row = m0 + wm + i * 16 + quad * 4 + r;
        float v = acc[i][j][r] + bv;
        if (EP == 0) {
          v = v > 0.f ? v : 0.f;
          ((ushort*)Cv)[(size_t)row * ldc + col] = f2bf(v);
        } else if (EP == 1) {
          ((float*)Cv)[(size_t)row * ldc + col] = v;
        } else {
          ((float*)Cv)[(size_t)row * ldc + col] += v;
        }
      }
    }
  }
}

// ---------------------------------------------------------------------------
// 256x256 8-phase GEMM (T2+T3+T4+T5 template), now z-batched:
//  A += z*az, B += z*bz; EP0 C += z*cz (ushort elems); EP1 z>0 writes C1.
//  bias: bb = bias + z*bias_zstride + (idxp ? idxp[sel0 + z*sel_zmul]*bstride : 0)
// Inner schedule identical to R1 (verified): 8 phases / 2 K-tiles, counted
// vmcnt(4) at ph4/ph8 only, chunk-XOR swizzle on both stage-source and
// ds_read (involution), setprio around each 16-MFMA quadrant.
// ---------------------------------------------------------------------------
#define BAR() __builtin_amdgcn_s_barrier()
#define SCHEDB() __builtin_amdgcn_sched_barrier(0)
#define WAITLGKM() asm volatile("s_waitcnt lgkmcnt(0)" ::: "memory")
#define WAITVM(N) asm volatile("s_waitcnt vmcnt(" #N ")" ::: "memory")

#define STG(BASE, LD, ARR, P, H, KT)                                                        \
  do {                                                                                      \
    const int kt_ = ((KT) < ntile) ? (KT) : (ntile - 1);                                    \
    const ushort* g_ = (BASE) + (size_t)(H) * 128 * (LD) + (size_t)kt_ * 64;                \
    __builtin_amdgcn_global_load_lds(                                                       \
        (const __attribute__((address_space(1))) void*)g_,                                  \
        (__attribute__((address_space(3))) void*)&ARR[(P) * 16384 + (H) * 8192 + w * 512],  \
        16, 0, 0);                                                                          \
    __builtin_amdgcn_global_load_lds(                                                       \
        (const __attribute__((address_space(1))) void*)(g_ + (size_t)64 * (LD)),            \
        (__attribute__((address_space(3))) void*)&ARR[(P) * 16384 + (H) * 8192 + 4096 +     \
                                                      w * 512],                             \
        16, 0, 0);                                                                          \
  } while (0)

#define RD_A(P, MH)                                                                         \
  do {                                                                                      \
    _Pragma("unroll") for (int mf = 0; mf < 4; ++mf)                                        \
    _Pragma("unroll") for (int kk = 0; kk < 2; ++kk)                                        \
        af[mf][kk] = *(const bf16x8*)&As[(P) * 16384 + ak[kk] + ((MH) * 4 + mf) * 1024];    \
  } while (0)

#define RD_B(P, NH)                                                                         \
  do {                                                                                      \
    _Pragma("unroll") for (int nf = 0; nf < 2; ++nf)                                        \
    _Pragma("unroll") for (int kk = 0; kk < 2; ++kk)                                        \
        bfr[(NH) * 2 + nf][kk] =                                                            \
            *(const bf16x8*)&Bs[(P) * 16384 + bk[kk] + ((NH) * 2 + nf) * 1024];             \
  } while (0)

#define MFMA_Q(MH, NH)                                                                      \
  do {                                                                                      \
    __builtin_amdgcn_s_setprio(1);                                                          \
    _Pragma("unroll") for (int mf = 0; mf < 4; ++mf)                                        \
    _Pragma("unroll") for (int nf = 0; nf < 2; ++nf)                                        \
    _Pragma("unroll") for (int kk = 0; kk < 2; ++kk)                                        \
        acc[(MH) * 4 + mf][(NH) * 2 + nf] = __builtin_amdgcn_mfma_f32_16x16x32_bf16(        \
            af[mf][kk], bfr[(NH) * 2 + nf][kk], acc[(MH) * 4 + mf][(NH) * 2 + nf], 0, 0, 0);\
    __builtin_amdgcn_s_setprio(0);                                                          \
  } while (0)

template <int EP>
__global__ __launch_bounds__(512, 2) void gemm256(
    const ushort* __restrict__ A, int lda, long az,
    const ushort* __restrict__ B, int ldb, long bz,
    const float* __restrict__ bias, long bias_zstride,
    const int* __restrict__ idxp, int sel0, int sel_zmul, int bstride,
    void* __restrict__ Cv, int ldc, long cz, float* __restrict__ C1,
    int K) {
  __shared__ __align__(16) ushort As[32768];
  __shared__ __align__(16) ushort Bs[32768];
  const int tid = threadIdx.x;
  const int w = tid >> 6;
  const int lane = tid & 63;
  const int quad = lane >> 4;
  const int l16 = lane & 15;
  const int wr = w >> 2;
  const int wc = w & 3;
  const int z = blockIdx.z;

  A += (size_t)z * az;
  B += (size_t)z * bz;

  // Bijective XCD swizzle per z-slice (m204).
  const int GX = gridDim.x;
  const int nwg = GX * gridDim.y;
  const int fid = blockIdx.y * GX + blockIdx.x;
  const int q8 = nwg >> 3, r8 = nwg & 7, xcd = fid & 7, ser = fid >> 3;
  const int wg = (xcd < r8 ? xcd * (q8 + 1) : r8 * (q8 + 1) + (xcd - r8) * q8) + ser;
  const int m0 = (wg / GX) * 256;
  const int n0 = (wg % GX) * 256;

  f32x4 acc[8][4];
#pragma unroll
  for (int i = 0; i < 8; ++i)
#pragma unroll
    for (int j = 0; j < 4; ++j)
#pragma unroll
      for (int r = 0; r < 4; ++r) acc[i][j][r] = 0.f;

  const int srow = tid >> 3;
  const int scol = (tid & 7) ^ (srow & 7);
  const ushort* Abase = A + (size_t)(m0 + srow) * lda + scol * 8;
  const ushort* Bbase = B + (size_t)(n0 + srow) * ldb + scol * 8;
  const int ntile = K >> 6;
  const int ni = ntile >> 1;

  int ak[2], bk[2];
#pragma unroll
  for (int kk = 0; kk < 2; ++kk) {
    const int ch = ((kk * 4 + quad) ^ (l16 & 7)) * 8;
    ak[kk] = wr * 8192 + l16 * 64 + ch;
    bk[kk] = (wc >> 1) * 8192 + ((wc & 1) * 64 + l16) * 64 + ch;
  }

  STG(Abase, lda, As, 0, 0, 0);
  STG(Abase, lda, As, 0, 1, 0);
  STG(Bbase, ldb, Bs, 0, 0, 0);
  STG(Bbase, ldb, Bs, 0, 1, 0);
  STG(Bbase, ldb, Bs, 1, 0, 1);
  STG(Bbase, ldb, Bs, 1, 1, 1);
  WAITVM(4);
  BAR();
  SCHEDB();

  bf16x8 af[4][2], bfr[4][2];
  for (int i = 0; i < ni; ++i) {
    const int t = 2 * i;
    RD_A(0, 0); RD_B(0, 0);
    STG(Abase, lda, As, 1, 0, t + 1);
    BAR(); WAITLGKM();
    MFMA_Q(0, 0);
    BAR();
    RD_B(0, 1);
    STG(Abase, lda, As, 1, 1, t + 1);
    BAR(); WAITLGKM();
    MFMA_Q(0, 1);
    BAR();
    RD_A(0, 1);
    STG(Bbase, ldb, Bs, 0, 0, t + 2);
    BAR(); WAITLGKM();
    MFMA_Q(1, 0);
    BAR();
    STG(Bbase, ldb, Bs, 0, 1, t + 2);
    WAITVM(4);
    BAR();
    SCHEDB();
    MFMA_Q(1, 1);
    BAR();
    RD_A(1, 0); RD_B(1, 0);
    STG(Abase, lda, As, 0, 0, t + 2);
    BAR(); WAITLGKM();
    MFMA_Q(0, 0);
    BAR();
    RD_B(1, 1);
    STG(Abase, lda, As, 0, 1, t + 2);
    BAR(); WAITLGKM();
    MFMA_Q(0, 1);
    BAR();
    RD_A(1, 1);
    STG(Bbase, ldb, Bs, 1, 0, t + 3);
    BAR(); WAITLGKM();
    MFMA_Q(1, 0);
    BAR();
    STG(Bbase, ldb, Bs, 1, 1, t + 3);
    WAITVM(4);
    BAR();
    SCHEDB();
    MFMA_Q(1, 1);
    BAR();
  }
  WAITVM(0);
  BAR();

  const float* bb = bias;
  if (bias) {
    bb += (size_t)z * bias_zstride;
    if (idxp) bb += (size_t)idxp[sel0 + z * sel_zmul] * bstride;
  }
  // z>0 EP1 slice writes the partial buffer WITHOUT bias (bias only on z=0).
  const bool nobias = (EP != 0) && (bias == nullptr || (z != 0 && C1 != nullptr));
  ushort* Cu = (EP == 0) ? (ushort*)Cv + (size_t)z * cz : nullptr;
  float* Cf = (EP == 0) ? nullptr : ((EP == 1 && z != 0 && C1) ? C1 : (float*)Cv);

#pragma unroll
  for (int mf = 0; mf < 8; ++mf) {
#pragma unroll
    for (int nf = 0; nf < 4; ++nf) {
      const int col = n0 + wc * 64 + nf * 16 + l16;
      const float bv = (EP == 2 || nobias) ? 0.f : bb[col];
#pragma unroll
      for (int r = 0; r < 4; ++r) {
        const int row = m0 + wr * 128 + mf * 16 + quad * 4 + r;
        float v = acc[mf][nf][r] + bv;
        if (EP == 0) {
          v = v > 0.f ? v : 0.f;
          Cu[(size_t)row * ldc + col] = f2bf(v);
        } else if (EP == 1) {
          Cf[(size_t)row * ldc + col] = v;
        } else {
          Cf[(size_t)row * ldc + col] += v;
        }
      }
    }
  }
}

extern "C" void kernel_launch(void* const* d_in, const int* in_sizes, int n_in,
                              void* d_out, int out_size, void* d_ws, size_t ws_size,
                              hipStream_t stream) {
  const float* x      = (const float*)d_in[0];
  const float* Wp     = (const float*)d_in[1];
  const float* bp     = (const float*)d_in[2];
  const float* Wop    = (const float*)d_in[3];
  const float* bop    = (const float*)d_in[4];
  const float* logits = (const float*)d_in[5];
  const float* Wr     = (const float*)d_in[6];
  const float* br     = (const float*)d_in[7];
  float* out = (float*)d_out;

  const size_t MB = 1024 * 1024;
  // Fused layout: idx(256B) xb(16M) WpB(16M) WrB(16M) W8(64M) xpcat(128M)
  //               hcat(128M) out1(32M)  => 400.25 MB
  const size_t need_fused = 256 + (size_t)(16 + 16 + 16 + 64 + 128 + 128 + 32) * MB;

  char* ws = (char*)d_ws;
  size_t off = 0;
  int* idx = (int*)ws;                          off += 256;
  ushort* xb   = (ushort*)(ws + off);           off += (size_t)Bn * Dd * 2;
  ushort* WpB  = (ushort*)(ws + off);           off += (size_t)Tt * Hh * Dd * 2;
  ushort* WrB  = (ushort*)(ws + off);           off += (size_t)Oo * TH * 2;

  top2_kernel<<<1, 64, 0, stream>>>(logits, idx);
  {
    int n4 = Bn * Dd / 4;
    cvt_bf16<<<(n4 + TB - 1) / TB, TB, 0, stream>>>(x, xb, n4);
  }
  {
    int n4 = Tt * Hh * Dd / 4;
    cvt_bf16<<<(n4 + TB - 1) / TB, TB, 0, stream>>>(Wp, WpB, n4);
  }
  {
    int n4 = Oo * TH / 4;
    cvt_bf16<<<(n4 + TB - 1) / TB, TB, 0, stream>>>(Wr, WrB, n4);
  }

  if (ws_size >= need_fused) {
    // ---------------- fused path ----------------
    ushort* W8    = (ushort*)(ws + off);        off += (size_t)8 * Hh * Hh * 2;
    ushort* xpcat = (ushort*)(ws + off);        off += (size_t)Bn * TH * 2;
    ushort* hcat  = (ushort*)(ws + off);        off += (size_t)Bn * TH * 2;
    float*  out1  = (float*)(ws + off);         off += (size_t)Bn * Oo * 4;

    {  // all 8 routed operator matrices at once
      int n4 = Hh * Hh / 4;
      dim3 g((n4 + TB - 1) / TB, 1, 8);
      cvt_sel8<<<g, TB, 0, stream>>>(Wop, idx, W8, n4);
    }

    // G1: xpcat[B, T*H] = relu(x @ Wpall^T + bpall)   (one 1024-wg dispatch)
    gemm256<0><<<dim3(TH / 256, Bn / 256, 1), 512, 0, stream>>>(
        xb, Dd, 0, WpB, Dd, 0, bp, 0, nullptr, 0, 0, 0, xpcat, TH, 0, nullptr, Dd);

    // G2 (z=temper): hcat_z = relu(xpcat_z @ Wa_z^T + ba_z)
    gemm256<0><<<dim3(Hh / 256, Bn / 256, Tt), 512, 0, stream>>>(
        xpcat, TH, Hh, W8, Hh, (long)2 * Hh * Hh,
        bop, (long)NO * Hh, idx, 0, 2, Hh, hcat, TH, Hh, nullptr, Hh);

    // G3 (z=temper): xpcat_z = relu(hcat_z @ Wb_z^T + bb_z)   (overwrites xp)
    gemm256<0><<<dim3(Hh / 256, Bn / 256, Tt), 512, 0, stream>>>(
        hcat, TH, Hh, W8 + (size_t)Hh * Hh, Hh, (long)2 * Hh * Hh,
        bop, (long)NO * Hh, idx, 1, 2, Hh, xpcat, TH, Hh, nullptr, Hh);

    // Readout split-K=2: z=0 -> out (+br), z=1 -> out1; then out += out1.
    gemm256<1><<<dim3(Oo / 256, Bn / 256, 2), 512, 0, stream>>>(
        xpcat, TH, (long)TH / 2, WrB, TH, (long)TH / 2,
        br, 0, nullptr, 0, 0, 0, out, Oo, 0, out1, TH / 2);
    {
      int n4 = Bn * Oo / 4;
      add_f32<<<(n4 + TB - 1) / TB, TB, 0, stream>>>(out, out1, n4);
    }
  } else {
    // ---------------- fallback path (R1 structure, 128.25 MB) ----------------
    ushort* WaB  = (ushort*)(ws + off);         off += (size_t)Hh * Hh * 2;
    ushort* WbB  = (ushort*)(ws + off);         off += (size_t)Hh * Hh * 2;
    ushort* bufA = (ushort*)(ws + off);         off += (size_t)Bn * Hh * 2;
    ushort* bufB = (ushort*)(ws + off);         off += (size_t)Bn * Hh * 2;

    dim3 g256(Hh / 256, Bn / 256);
    dim3 gOB(Oo / 128, Bn / 128);

    for (int t = 0; t < Tt; ++t) {
      int n4 = Hh * Hh / 4;
      cvt_sel<<<(n4 + TB - 1) / TB, TB, 0, stream>>>(Wop + (size_t)t * NO * Hh * Hh,
                                                     idx + 2 * t, WaB, WbB, n4);
      gemm256<0><<<g256, 512, 0, stream>>>(
          xb, Dd, 0, WpB + (size_t)t * Hh * Dd, Dd, 0,
          bp + (size_t)t * Hh, 0, nullptr, 0, 0, 0, bufA, Hh, 0, nullptr, Dd);
      gemm256<0><<<g256, 512, 0, stream>>>(
          bufA, Hh, 0, WaB, Hh, 0,
          bop + (size_t)t * NO * Hh, 0, idx, 2 * t, 0, Hh, bufB, Hh, 0, nullptr, Hh);
      gemm256<0><<<g256, 512, 0, stream>>>(
          bufB, Hh, 0, WbB, Hh, 0,
          bop + (size_t)t * NO * Hh, 0, idx, 2 * t + 1, 0, Hh, bufA, Hh, 0, nullptr, Hh);
      if (t == 0)
        gemm_bt<1><<<gOB, TB, 0, stream>>>(bufA, Hh, WrB + (size_t)t * Hh, TH,
                                           br, nullptr, 0, 0, out, Oo, Hh);
      else
        gemm_bt<2><<<gOB, TB, 0, stream>>>(bufA, Hh, WrB + (size_t)t * Hh, TH,
                                           nullptr, nullptr, 0, 0, out, Oo, Hh);
    }
  }
}

// Round 3
// 1172.727 us; speedup vs baseline: 1.2482x; 1.0206x over previous
//
#include <hip/hip_runtime.h>

// Problem constants (B, D, H, O, T, NOPS from reference)
static constexpr int Bn = 8192;
static constexpr int Dd = 1024;
static constexpr int Hh = 2048;
static constexpr int Oo = 1024;
static constexpr int Tt = 4;
static constexpr int NO = 3;
static constexpr int TH = Tt * Hh;  // 8192
#define TB 256

typedef __attribute__((ext_vector_type(8))) short bf16x8;
typedef __attribute__((ext_vector_type(4))) float f32x4;

__device__ __forceinline__ ushort f2bf(float f) {
  union { float f; unsigned u; } v; v.f = f;
  return (ushort)((v.u + 0x7FFFu + ((v.u >> 16) & 1u)) >> 16);  // RNE
}

// Top-2 of logits per temper (softmax is monotonic; jax top_k ties -> lower idx).
__global__ void top2_kernel(const float* __restrict__ logits, int* __restrict__ idx) {
  if (threadIdx.x == 0 && blockIdx.x == 0) {
    for (int t = 0; t < Tt; ++t) {
      const float* lg = logits + t * NO;
      int i0 = 0;
      for (int k = 1; k < NO; ++k) if (lg[k] > lg[i0]) i0 = k;
      int i1 = -1;
      for (int k = 0; k < NO; ++k) {
        if (k == i0) continue;
        if (i1 < 0 || lg[k] > lg[i1]) i1 = k;
      }
      idx[2 * t] = i0;
      idx[2 * t + 1] = i1;
    }
  }
}

__global__ void cvt_bf16(const float* __restrict__ src, ushort* __restrict__ dst, int n4) {
  int i = blockIdx.x * blockDim.x + threadIdx.x;
  if (i >= n4) return;
  float4 v = ((const float4*)src)[i];
  ((ushort4*)dst)[i] = make_ushort4(f2bf(v.x), f2bf(v.y), f2bf(v.z), f2bf(v.w));
}

// Convert the two routed operator matrices for ONE temper (fallback path).
__global__ void cvt_sel(const float* __restrict__ WopT, const int* __restrict__ idx2,
                        ushort* __restrict__ Wa, ushort* __restrict__ Wb, int n4) {
  int i = blockIdx.x * blockDim.x + threadIdx.x;
  if (i >= n4) return;
  size_t n = (size_t)n4 * 4;
  float4 va = ((const float4*)(WopT + (size_t)idx2[0] * n))[i];
  float4 vb = ((const float4*)(WopT + (size_t)idx2[1] * n))[i];
  ((ushort4*)Wa)[i] = make_ushort4(f2bf(va.x), f2bf(va.y), f2bf(va.z), f2bf(va.w));
  ((ushort4*)Wb)[i] = make_ushort4(f2bf(vb.x), f2bf(vb.y), f2bf(vb.z), f2bf(vb.w));
}

// Convert ALL 8 routed matrices (fused path). z = t*2 + slot -> W8[z] layout.
__global__ void cvt_sel8(const float* __restrict__ Wop, const int* __restrict__ idx,
                         ushort* __restrict__ W8, int n4) {
  int i = blockIdx.x * blockDim.x + threadIdx.x;
  if (i >= n4) return;
  int z = blockIdx.z;
  int t = z >> 1, slot = z & 1;
  int op = idx[2 * t + slot];
  const float4* src = (const float4*)(Wop + ((size_t)t * NO + op) * Hh * Hh);
  float4 v = src[i];
  ((ushort4*)(W8 + (size_t)z * Hh * Hh))[i] =
      make_ushort4(f2bf(v.x), f2bf(v.y), f2bf(v.z), f2bf(v.w));
}

// out += p1 (split-K reduction for the fused readout)
__global__ void add_f32(float* __restrict__ out, const float* __restrict__ p1, int n4) {
  int i = blockIdx.x * blockDim.x + threadIdx.x;
  if (i >= n4) return;
  float4 a = ((const float4*)out)[i];
  float4 b = ((const float4*)p1)[i];
  a.x += b.x; a.y += b.y; a.z += b.z; a.w += b.w;
  ((float4*)out)[i] = a;
}

#define ISSUE_TILE(kk, p)                                                                   \
  do {                                                                                      \
    __builtin_amdgcn_global_load_lds(                                                       \
        (const __attribute__((address_space(1))) void*)(a0 + (kk)),                         \
        (__attribute__((address_space(3))) void*)(&As[p][w * 512]), 16, 0, 0);              \
    __builtin_amdgcn_global_load_lds(                                                       \
        (const __attribute__((address_space(1))) void*)(a1 + (kk)),                         \
        (__attribute__((address_space(3))) void*)(&As[p][2048 + w * 512]), 16, 0, 0);       \
    __builtin_amdgcn_global_load_lds(                                                       \
        (const __attribute__((address_space(1))) void*)(b0 + (kk)),                         \
        (__attribute__((address_space(3))) void*)(&Bs[p][w * 512]), 16, 0, 0);              \
    __builtin_amdgcn_global_load_lds(                                                       \
        (const __attribute__((address_space(1))) void*)(b1 + (kk)),                         \
        (__attribute__((address_space(3))) void*)(&Bs[p][2048 + w * 512]), 16, 0, 0);       \
  } while (0)

// 128x128-tile m97-class GEMM (fallback readout only).
template <int EP>
__global__ __launch_bounds__(TB) void gemm_bt(
    const ushort* __restrict__ A, int lda,
    const ushort* __restrict__ B, int ldb,
    const float* __restrict__ bias, const int* __restrict__ idxp, int sel, int bstride,
    void* __restrict__ Cv, int ldc, int K) {
  __shared__ __align__(16) ushort As[2][128 * 32];
  __shared__ __align__(16) ushort Bs[2][128 * 32];
  const int tid = threadIdx.x;
  const int w = tid >> 6;
  const int lane = tid & 63;
  const int quad = lane >> 4;
  const int l16 = lane & 15;

  const int GX = gridDim.x, GY = gridDim.y;
  const int f = blockIdx.y * GX + blockIdx.x;
  const int xcd = f & 7;
  const int s = f >> 3;
  const int pxc = (GX >= 16) ? 2 : 1;
  const int pw = GX / pxc;
  const int ph = (GY * pxc) >> 3;
  const int bx = (xcd % pxc) * pw + (s % pw);
  const int by = (xcd / pxc) * ph + (s / pw);
  const int m0 = by * 128;
  const int n0 = bx * 128;
  const int wm = (w >> 1) * 64;
  const int wn = (w & 1) * 64;

  f32x4 acc[4][4];
#pragma unroll
  for (int i = 0; i < 4; ++i)
#pragma unroll
    for (int j = 0; j < 4; ++j)
#pragma unroll
      for (int r = 0; r < 4; ++r) acc[i][j][r] = 0.f;

  const int srow = tid >> 2;
  const int skc = ((tid & 3) ^ ((tid >> 3) & 3)) * 8;
  const ushort* a0 = A + (size_t)(m0 + srow) * lda + skc;
  const ushort* a1 = A + (size_t)(m0 + 64 + srow) * lda + skc;
  const ushort* b0 = B + (size_t)(n0 + srow) * ldb + skc;
  const ushort* b1 = B + (size_t)(n0 + 64 + srow) * ldb + skc;

  const int fq = (quad ^ ((l16 >> 1) & 3)) * 8;

  const int niter = K >> 5;
  ISSUE_TILE(0, 0);
  for (int it = 0; it < niter; ++it) {
    const int p = it & 1;
    __syncthreads();
    if (it + 1 < niter) ISSUE_TILE((it + 1) << 5, p ^ 1);

    bf16x8 af[4], bfr[4];
#pragma unroll
    for (int i = 0; i < 4; ++i)
      af[i] = *(const bf16x8*)&As[p][((wm >> 4) + i) * 512 + l16 * 32 + fq];
#pragma unroll
    for (int j = 0; j < 4; ++j)
      bfr[j] = *(const bf16x8*)&Bs[p][((wn >> 4) + j) * 512 + l16 * 32 + fq];
#pragma unroll
    for (int i = 0; i < 4; ++i)
#pragma unroll
      for (int j = 0; j < 4; ++j)
        acc[i][j] = __builtin_amdgcn_mfma_f32_16x16x32_bf16(af[i], bfr[j], acc[i][j], 0, 0, 0);
  }

  const float* bb = bias;
  if (EP == 0 && idxp) bb += (size_t)idxp[sel] * bstride;

#pragma unroll
  for (int i = 0; i < 4; ++i) {
#pragma unroll
    for (int j = 0; j < 4; ++j) {
      const int col = n0 + wn + j * 16 + l16;
      const float bv = (EP == 2 || !bias) ? 0.f : bb[col];
#pragma unroll
      for (int r = 0; r < 4; ++r) {
        const int row = m0 + wm + i * 16 + quad * 4 + r;
        float v = acc[i][j][r] + bv;
        if (EP == 0) {
          v = v > 0.f ? v : 0.f;
          ((ushort*)Cv)[(size_t)row * ldc + col] = f2bf(v);
        } else if (EP == 1) {
          ((float*)Cv)[(size_t)row * ldc + col] = v;
        } else {
          ((float*)Cv)[(size_t)row * ldc + col] += v;
        }
      }
    }
  }
}

// ---------------------------------------------------------------------------
// 256x256 8-phase GEMM (T2+T3+T4+T5), z-batched, DEEP-PREFETCH schedule (R3):
// stage whole tile t+2 at ph3(B)+ph4(A), tile t+3 at ph7(B)+ph8(A);
// vmcnt(8) at ph4/ph8 leaves exactly those 2 tiles (8 loads) in flight, so the
// youngest load each wait drains was issued 4 phases (~600 cyc) earlier
// (R2's vmcnt(4) drained 2-phase-old loads -> ~500cyc HBM stall twice/iter,
// MfmaUtil 38%).  Region liveness: B-buf frees after ph2/ph6 (last RD), A-buf
// after ph3/ph7 -> every STG issues after its region's last-reader barrier.
// Prologue: tile0+tile1 (16 loads), wait-to-8 drains tile0 only.
// ---------------------------------------------------------------------------
#define BAR() __builtin_amdgcn_s_barrier()
#define SCHEDB() __builtin_amdgcn_sched_barrier(0)
#define WAITLGKM() asm volatile("s_waitcnt lgkmcnt(0)" ::: "memory")
#define WAITVM(N) asm volatile("s_waitcnt vmcnt(" #N ")" ::: "memory")

#define STG(BASE, LD, ARR, P, H, KT)                                                        \
  do {                                                                                      \
    const int kt_ = ((KT) < ntile) ? (KT) : (ntile - 1);                                    \
    const ushort* g_ = (BASE) + (size_t)(H) * 128 * (LD) + (size_t)kt_ * 64;                \
    __builtin_amdgcn_global_load_lds(                                                       \
        (const __attribute__((address_space(1))) void*)g_,                                  \
        (__attribute__((address_space(3))) void*)&ARR[(P) * 16384 + (H) * 8192 + w * 512],  \
        16, 0, 0);                                                                          \
    __builtin_amdgcn_global_load_lds(                                                       \
        (const __attribute__((address_space(1))) void*)(g_ + (size_t)64 * (LD)),            \
        (__attribute__((address_space(3))) void*)&ARR[(P) * 16384 + (H) * 8192 + 4096 +     \
                                                      w * 512],                             \
        16, 0, 0);                                                                          \
  } while (0)

#define RD_A(P, MH)                                                                         \
  do {                                                                                      \
    _Pragma("unroll") for (int mf = 0; mf < 4; ++mf)                                        \
    _Pragma("unroll") for (int kk = 0; kk < 2; ++kk)                                        \
        af[mf][kk] = *(const bf16x8*)&As[(P) * 16384 + ak[kk] + ((MH) * 4 + mf) * 1024];    \
  } while (0)

#define RD_B(P, NH)                                                                         \
  do {                                                                                      \
    _Pragma("unroll") for (int nf = 0; nf < 2; ++nf)                                        \
    _Pragma("unroll") for (int kk = 0; kk < 2; ++kk)                                        \
        bfr[(NH) * 2 + nf][kk] =                                                            \
            *(const bf16x8*)&Bs[(P) * 16384 + bk[kk] + ((NH) * 2 + nf) * 1024];             \
  } while (0)

#define MFMA_Q(MH, NH)                                                                      \
  do {                                                                                      \
    __builtin_amdgcn_s_setprio(1);                                                          \
    _Pragma("unroll") for (int mf = 0; mf < 4; ++mf)                                        \
    _Pragma("unroll") for (int nf = 0; nf < 2; ++nf)                                        \
    _Pragma("unroll") for (int kk = 0; kk < 2; ++kk)                                        \
        acc[(MH) * 4 + mf][(NH) * 2 + nf] = __builtin_amdgcn_mfma_f32_16x16x32_bf16(        \
            af[mf][kk], bfr[(NH) * 2 + nf][kk], acc[(MH) * 4 + mf][(NH) * 2 + nf], 0, 0, 0);\
    __builtin_amdgcn_s_setprio(0);                                                          \
  } while (0)

template <int EP>
__global__ __launch_bounds__(512, 2) void gemm256(
    const ushort* __restrict__ A, int lda, long az,
    const ushort* __restrict__ B, int ldb, long bz,
    const float* __restrict__ bias, long bias_zstride,
    const int* __restrict__ idxp, int sel0, int sel_zmul, int bstride,
    void* __restrict__ Cv, int ldc, long cz, float* __restrict__ C1,
    int K) {
  __shared__ __align__(16) ushort As[32768];
  __shared__ __align__(16) ushort Bs[32768];
  const int tid = threadIdx.x;
  const int w = tid >> 6;
  const int lane = tid & 63;
  const int quad = lane >> 4;
  const int l16 = lane & 15;
  const int wr = w >> 2;
  const int wc = w & 3;
  const int z = blockIdx.z;

  A += (size_t)z * az;
  B += (size_t)z * bz;

  // Bijective XCD swizzle per z-slice (m204).
  const int GX = gridDim.x;
  const int nwg = GX * gridDim.y;
  const int fid = blockIdx.y * GX + blockIdx.x;
  const int q8 = nwg >> 3, r8 = nwg & 7, xcd = fid & 7, ser = fid >> 3;
  const int wg = (xcd < r8 ? xcd * (q8 + 1) : r8 * (q8 + 1) + (xcd - r8) * q8) + ser;
  const int m0 = (wg / GX) * 256;
  const int n0 = (wg % GX) * 256;

  f32x4 acc[8][4];
#pragma unroll
  for (int i = 0; i < 8; ++i)
#pragma unroll
    for (int j = 0; j < 4; ++j)
#pragma unroll
      for (int r = 0; r < 4; ++r) acc[i][j][r] = 0.f;

  // Routing index: load BEFORE the prologue and pin it so no VMEM/SMEM op for
  // it can appear inside the counted-vmcnt loop (oldest loads drain first).
  int route = 0;
  if (idxp) route = idxp[sel0 + z * sel_zmul];
  asm volatile("" : "+v"(route));

  const int srow = tid >> 3;
  const int scol = (tid & 7) ^ (srow & 7);
  const ushort* Abase = A + (size_t)(m0 + srow) * lda + scol * 8;
  const ushort* Bbase = B + (size_t)(n0 + srow) * ldb + scol * 8;
  const int ntile = K >> 6;
  const int ni = ntile >> 1;

  int ak[2], bk[2];
#pragma unroll
  for (int kk = 0; kk < 2; ++kk) {
    const int ch = ((kk * 4 + quad) ^ (l16 & 7)) * 8;
    ak[kk] = wr * 8192 + l16 * 64 + ch;
    bk[kk] = (wc >> 1) * 8192 + ((wc & 1) * 64 + l16) * 64 + ch;
  }

  // Prologue: tile0 (A,B) + tile1 (B,A) = 16 loads; drain tile0, keep tile1.
  STG(Abase, lda, As, 0, 0, 0);
  STG(Abase, lda, As, 0, 1, 0);
  STG(Bbase, ldb, Bs, 0, 0, 0);
  STG(Bbase, ldb, Bs, 0, 1, 0);
  STG(Bbase, ldb, Bs, 1, 0, 1);
  STG(Bbase, ldb, Bs, 1, 1, 1);
  STG(Abase, lda, As, 1, 0, 1);
  STG(Abase, lda, As, 1, 1, 1);
  WAITVM(8);
  BAR();
  SCHEDB();

  bf16x8 af[4][2], bfr[4][2];
  for (int i = 0; i < ni; ++i) {
    const int t = 2 * i;
    // ---- tile t (buf0) ----
    // ph1: 12 ds_read, no staging
    RD_A(0, 0); RD_B(0, 0);
    BAR(); WAITLGKM();
    MFMA_Q(0, 0);
    BAR();
    // ph2: 4 ds_read
    RD_B(0, 1);
    BAR(); WAITLGKM();
    MFMA_Q(0, 1);
    BAR();
    // ph3: 8 ds_read + stage B(t+2) both halves (B-buf0 free after ph2)
    RD_A(0, 1);
    STG(Bbase, ldb, Bs, 0, 0, t + 2);
    STG(Bbase, ldb, Bs, 0, 1, t + 2);
    BAR(); WAITLGKM();
    MFMA_Q(1, 0);
    BAR();
    // ph4: stage A(t+2) (A-buf0 free after ph3); counted vmcnt(8):
    // leaves tile t+2's 8 loads in flight, drains tile t+1 (staged prev
    // ph7/ph8, 4 phases ago) for ph5's reads.
    STG(Abase, lda, As, 0, 0, t + 2);
    STG(Abase, lda, As, 0, 1, t + 2);
    WAITVM(8);
    BAR();
    SCHEDB();
    MFMA_Q(1, 1);
    BAR();
    // ---- tile t+1 (buf1) ----
    // ph5
    RD_A(1, 0); RD_B(1, 0);
    BAR(); WAITLGKM();
    MFMA_Q(0, 0);
    BAR();
    // ph6
    RD_B(1, 1);
    BAR(); WAITLGKM();
    MFMA_Q(0, 1);
    BAR();
    // ph7: stage B(t+3) (B-buf1 free after ph6)
    RD_A(1, 1);
    STG(Bbase, ldb, Bs, 1, 0, t + 3);
    STG(Bbase, ldb, Bs, 1, 1, t + 3);
    BAR(); WAITLGKM();
    MFMA_Q(1, 0);
    BAR();
    // ph8: stage A(t+3); vmcnt(8) leaves tile t+3, drains tile t+2.
    STG(Abase, lda, As, 1, 0, t + 3);
    STG(Abase, lda, As, 1, 1, t + 3);
    WAITVM(8);
    BAR();
    SCHEDB();
    MFMA_Q(1, 1);
    BAR();
  }
  WAITVM(0);  // drain clamped tail prefetches
  BAR();

  const float* bb = bias;
  if (bias) {
    bb += (size_t)z * bias_zstride;
    if (idxp) bb += (size_t)route * bstride;
  }
  const bool nobias = (EP != 0) && (bias == nullptr || (z != 0 && C1 != nullptr));
  ushort* Cu = (EP == 0) ? (ushort*)Cv + (size_t)z * cz : nullptr;
  float* Cf = (EP == 0) ? nullptr : ((EP == 1 && z != 0 && C1) ? C1 : (float*)Cv);

#pragma unroll
  for (int mf = 0; mf < 8; ++mf) {
#pragma unroll
    for (int nf = 0; nf < 4; ++nf) {
      const int col = n0 + wc * 64 + nf * 16 + l16;
      const float bv = (EP == 2 || nobias) ? 0.f : bb[col];
#pragma unroll
      for (int r = 0; r < 4; ++r) {
        const int row = m0 + wr * 128 + mf * 16 + quad * 4 + r;
        float v = acc[mf][nf][r] + bv;
        if (EP == 0) {
          v = v > 0.f ? v : 0.f;
          Cu[(size_t)row * ldc + col] = f2bf(v);
        } else if (EP == 1) {
          Cf[(size_t)row * ldc + col] = v;
        } else {
          Cf[(size_t)row * ldc + col] += v;
        }
      }
    }
  }
}

extern "C" void kernel_launch(void* const* d_in, const int* in_sizes, int n_in,
                              void* d_out, int out_size, void* d_ws, size_t ws_size,
                              hipStream_t stream) {
  const float* x      = (const float*)d_in[0];
  const float* Wp     = (const float*)d_in[1];
  const float* bp     = (const float*)d_in[2];
  const float* Wop    = (const float*)d_in[3];
  const float* bop    = (const float*)d_in[4];
  const float* logits = (const float*)d_in[5];
  const float* Wr     = (const float*)d_in[6];
  const float* br     = (const float*)d_in[7];
  float* out = (float*)d_out;

  const size_t MB = 1024 * 1024;
  const size_t need_fused = 256 + (size_t)(16 + 16 + 16 + 64 + 128 + 128 + 32) * MB;

  char* ws = (char*)d_ws;
  size_t off = 0;
  int* idx = (int*)ws;                          off += 256;
  ushort* xb   = (ushort*)(ws + off);           off += (size_t)Bn * Dd * 2;
  ushort* WpB  = (ushort*)(ws + off);           off += (size_t)Tt * Hh * Dd * 2;
  ushort* WrB  = (ushort*)(ws + off);           off += (size_t)Oo * TH * 2;

  top2_kernel<<<1, 64, 0, stream>>>(logits, idx);
  {
    int n4 = Bn * Dd / 4;
    cvt_bf16<<<(n4 + TB - 1) / TB, TB, 0, stream>>>(x, xb, n4);
  }
  {
    int n4 = Tt * Hh * Dd / 4;
    cvt_bf16<<<(n4 + TB - 1) / TB, TB, 0, stream>>>(Wp, WpB, n4);
  }
  {
    int n4 = Oo * TH / 4;
    cvt_bf16<<<(n4 + TB - 1) / TB, TB, 0, stream>>>(Wr, WrB, n4);
  }

  if (ws_size >= need_fused) {
    // ---------------- fused path ----------------
    ushort* W8    = (ushort*)(ws + off);        off += (size_t)8 * Hh * Hh * 2;
    ushort* xpcat = (ushort*)(ws + off);        off += (size_t)Bn * TH * 2;
    ushort* hcat  = (ushort*)(ws + off);        off += (size_t)Bn * TH * 2;
    float*  out1  = (float*)(ws + off);         off += (size_t)Bn * Oo * 4;

    {
      int n4 = Hh * Hh / 4;
      dim3 g((n4 + TB - 1) / TB, 1, 8);
      cvt_sel8<<<g, TB, 0, stream>>>(Wop, idx, W8, n4);
    }

    // G1: xpcat[B, T*H] = relu(x @ Wpall^T + bpall)
    gemm256<0><<<dim3(TH / 256, Bn / 256, 1), 512, 0, stream>>>(
        xb, Dd, 0, WpB, Dd, 0, bp, 0, nullptr, 0, 0, 0, xpcat, TH, 0, nullptr, Dd);

    // G2 (z=temper): hcat_z = relu(xpcat_z @ Wa_z^T + ba_z)
    gemm256<0><<<dim3(Hh / 256, Bn / 256, Tt), 512, 0, stream>>>(
        xpcat, TH, Hh, W8, Hh, (long)2 * Hh * Hh,
        bop, (long)NO * Hh, idx, 0, 2, Hh, hcat, TH, Hh, nullptr, Hh);

    // G3 (z=temper): xpcat_z = relu(hcat_z @ Wb_z^T + bb_z)
    gemm256<0><<<dim3(Hh / 256, Bn / 256, Tt), 512, 0, stream>>>(
        hcat, TH, Hh, W8 + (size_t)Hh * Hh, Hh, (long)2 * Hh * Hh,
        bop, (long)NO * Hh, idx, 1, 2, Hh, xpcat, TH, Hh, nullptr, Hh);

    // Readout split-K=2: z=0 -> out (+br), z=1 -> out1; then out += out1.
    gemm256<1><<<dim3(Oo / 256, Bn / 256, 2), 512, 0, stream>>>(
        xpcat, TH, (long)TH / 2, WrB, TH, (long)TH / 2,
        br, 0, nullptr, 0, 0, 0, out, Oo, 0, out1, TH / 2);
    {
      int n4 = Bn * Oo / 4;
      add_f32<<<(n4 + TB - 1) / TB, TB, 0, stream>>>(out, out1, n4);
    }
  } else {
    // ---------------- fallback path ----------------
    ushort* WaB  = (ushort*)(ws + off);         off += (size_t)Hh * Hh * 2;
    ushort* WbB  = (ushort*)(ws + off);         off += (size_t)Hh * Hh * 2;
    ushort* bufA = (ushort*)(ws + off);         off += (size_t)Bn * Hh * 2;
    ushort* bufB = (ushort*)(ws + off);         off += (size_t)Bn * Hh * 2;

    dim3 g256(Hh / 256, Bn / 256);
    dim3 gOB(Oo / 128, Bn / 128);

    for (int t = 0; t < Tt; ++t) {
      int n4 = Hh * Hh / 4;
      cvt_sel<<<(n4 + TB - 1) / TB, TB, 0, stream>>>(Wop + (size_t)t * NO * Hh * Hh,
                                                     idx + 2 * t, WaB, WbB, n4);
      gemm256<0><<<g256, 512, 0, stream>>>(
          xb, Dd, 0, WpB + (size_t)t * Hh * Dd, Dd, 0,
          bp + (size_t)t * Hh, 0, nullptr, 0, 0, 0, bufA, Hh, 0, nullptr, Dd);
      gemm256<0><<<g256, 512, 0, stream>>>(
          bufA, Hh, 0, WaB, Hh, 0,
          bop + (size_t)t * NO * Hh, 0, idx, 2 * t, 0, Hh, bufB, Hh, 0, nullptr, Hh);
      gemm256<0><<<g256, 512, 0, stream>>>(
          bufB, Hh, 0, WbB, Hh, 0,
          bop + (size_t)t * NO * Hh, 0, idx, 2 * t + 1, 0, Hh, bufA, Hh, 0, nullptr, Hh);
      if (t == 0)
        gemm_bt<1><<<gOB, TB, 0, stream>>>(bufA, Hh, WrB + (size_t)t * Hh, TH,
                                           br, nullptr, 0, 0, out, Oo, Hh);
      else
        gemm_bt<2><<<gOB, TB, 0, stream>>>(bufA, Hh, WrB + (size_t)t * Hh, TH,
                                           nullptr, nullptr, 0, 0, out, Oo, Hh);
    }
  }
}